// Round 3
// baseline (713.872 us; speedup 1.0000x reference)
//
#include <hip/hip_runtime.h>
#include <hip/hip_bf16.h>

#define B_   4
#define LQ_  4096
#define LS_  4096
#define DH_  1024
#define BQ_  64
#define BS_  256
#define NT_  16
#define NTH  512

typedef __bf16 bf16x8 __attribute__((ext_vector_type(8)));
typedef float  f32x4  __attribute__((ext_vector_type(4)));
typedef unsigned int u32;
typedef unsigned char u8;
typedef unsigned short u16;

#define WAITV(n) asm volatile("s_waitcnt vmcnt(" #n ")" ::: "memory")
#define WAITL()  asm volatile("s_waitcnt lgkmcnt(0)" ::: "memory")
#define SCHEDB() __builtin_amdgcn_sched_barrier(0)
#define BAR()    __builtin_amdgcn_s_barrier()

__device__ __forceinline__ void glds16(const void* g, void* l) {
  __builtin_amdgcn_global_load_lds(
      (const __attribute__((address_space(1))) u32*)g,
      (__attribute__((address_space(3))) u32*)l, 16, 0, 0);
}

__device__ __forceinline__ u16 f2bf(float f) {
  union { __bf16 h; u16 u; } cv; cv.h = (__bf16)f; return cv.u;
}
__device__ __forceinline__ bf16x8 cvt8(f32x4 a, f32x4 b) {
  bf16x8 r;
  r[0] = (__bf16)a[0]; r[1] = (__bf16)a[1]; r[2] = (__bf16)a[2]; r[3] = (__bf16)a[3];
  r[4] = (__bf16)b[0]; r[5] = (__bf16)b[1]; r[6] = (__bf16)b[2]; r[7] = (__bf16)b[3];
  return r;
}

// ---- fp32 S -> (a) SbT: QK chunks [b][t][c][256 s][64 d] bf16, XOR-pre-swizzled LDS image
//              (b) VT : PV chunks [b][t][k][1024 d][32 s] bf16, linear
__global__ __launch_bounds__(256) void cvt_kernel(const float* __restrict__ S,
                                                  u8* __restrict__ SbT,
                                                  u8* __restrict__ VT)
{
  __shared__ u16 tile[64][72];
  const int b  = blockIdx.z;
  const int dt = blockIdx.y;   // 0..15 (64-d chunk index c)
  const int st = blockIdx.x;   // 0..63 (64-s block)
  const int tid = threadIdx.x;
  const int t  = st >> 2;
  const float* Sbase = S + ((size_t)b*LS_ + (size_t)st*64)*DH_ + dt*64;
  u8* chunk = SbT + ((size_t)((b*NT_ + t)*16 + dt))*32768;

  #pragma unroll
  for (int k = 0; k < 4; ++k) {
    int fi  = tid + k*256;
    int row = fi >> 4;          // s within 64-block
    int c4  = fi & 15;          // 4-d group
    float4 v = *reinterpret_cast<const float4*>(Sbase + (size_t)row*DH_ + c4*4);
    ushort4 h;
    h.x = f2bf(v.x); h.y = f2bf(v.y); h.z = f2bf(v.z); h.w = f2bf(v.w);
    int s_loc = (st & 3)*64 + row;                       // 0..255 within chunk
    int byte  = s_loc*128 + ((c4*8) ^ ((s_loc & 7) << 4));
    *reinterpret_cast<ushort4*>(chunk + byte) = h;
    *reinterpret_cast<ushort4*>(&tile[row][c4*4]) = h;
  }
  __syncthreads();
  #pragma unroll
  for (int k = 0; k < 4; ++k) {
    int fo = tid + k*256;
    int dr = fo >> 4;           // d within 64-block
    int s4 = fo & 15;
    ushort4 h;
    h.x = tile[s4*4+0][dr]; h.y = tile[s4*4+1][dr];
    h.z = tile[s4*4+2][dr]; h.w = tile[s4*4+3][dr];
    int s_loc = (st & 3)*64 + s4*4;     // 0..255
    int kc = s_loc >> 5;                // 0..7 PV k-chunk
    int sl = s_loc & 31;
    u8* vchunk = VT + ((size_t)((b*NT_ + t)*8 + kc))*65536;
    *reinterpret_cast<ushort4*>(vchunk + (dt*64 + dr)*64 + sl*2) = h;
  }
}

// ---------------- fused flash attention, m==0 softmax, glds pipelined ----------------
__global__ __launch_bounds__(NTH, 2) void attn_kernel(
    const float* __restrict__ Qg,
    const u8* __restrict__ SbT,
    const u8* __restrict__ VT,
    float* __restrict__ Og)
{
  __shared__ __align__(16) u8 X[131072];   // QK: Bs 2x32K @0, Qf 2x16K @64K | PV: V 2x64K @0
  __shared__ __align__(16) u8 P[32768];    // P [64 q][256 s] bf16, swizzled; epilogue l-reduce

  const int tid = threadIdx.x;
  const int w  = tid >> 6, l = tid & 63;
  const int lg = l >> 4, lr = l & 15;
  const int n = blockIdx.x, xcd = n & 7, slot = n >> 3;
  const int b = xcd >> 1;                  // XCD pair per batch -> L2 sharing
  const int qt = (xcd & 1)*32 + slot;
  const int wq = w & 1, ws = w >> 1;

  const u8* Qb  = (const u8*)(Qg + ((size_t)b*LQ_ + (size_t)qt*BQ_)*DH_);
  const u8* SbB = SbT + (size_t)b*((size_t)NT_*16*32768);
  const u8* VTB = VT  + (size_t)b*((size_t)NT_*8*65536);

  u8* bs = X;            // 2 x 32768
  u8* qb = X + 65536;    // 2 x 16384
  u8* vb = X;            // 2 x 65536 (PV)

  f32x4 Oacc[4][8];
  #pragma unroll
  for (int i = 0; i < 4; ++i)
    #pragma unroll
    for (int j = 0; j < 8; ++j) Oacc[i][j] = (f32x4){0.f,0.f,0.f,0.f};
  float l_acc[2][4];
  #pragma unroll
  for (int i = 0; i < 2; ++i)
    #pragma unroll
    for (int j = 0; j < 4; ++j) l_acc[i][j] = 0.f;

  const int wl16 = (w << 10) + l*16;

  auto stageBs = [&](int t, int c, int buf) {
    const u8* src = SbB + ((size_t)(t*16 + c))*32768 + wl16;
    u8* dst = bs + buf*32768 + (w << 10);
    #pragma unroll
    for (int r = 0; r < 4; ++r) glds16(src + r*8192, dst + r*8192);
  };
  auto stageQ = [&](int c, int buf) {
    #pragma unroll
    for (int r = 0; r < 2; ++r) {
      int j = r*8192 + wl16;                 // byte within 16KB chunk image
      int q = j >> 8;                        // row (256 B fp32 rows)
      int colb = (j & 255) ^ ((q & 7) << 4); // inverse swizzle on SOURCE
      glds16(Qb + (size_t)q*4096 + c*256 + colb,
             qb + buf*16384 + r*8192 + (w << 10));
    }
  };
  auto stageV = [&](int t, int k, int buf) {
    const u8* src = VTB + ((size_t)(t*8 + k))*65536 + wl16;
    u8* dst = vb + buf*65536 + (w << 10);
    #pragma unroll
    for (int r = 0; r < 8; ++r) glds16(src + r*8192, dst + r*8192);
  };

  for (int t = 0; t < NT_; ++t) {
    // ================= QK^T : C[64 q][256 s] over d=1024, BK=64 =================
    f32x4 qk[2][4];
    #pragma unroll
    for (int i = 0; i < 2; ++i)
      #pragma unroll
      for (int j2 = 0; j2 < 4; ++j2) qk[i][j2] = (f32x4){0.f,0.f,0.f,0.f};

    stageBs(t, 0, 0); stageQ(0, 0);

    #pragma unroll
    for (int c = 0; c < 16; ++c) {
      if (c < 15) { stageBs(t, c+1, (c+1)&1); stageQ(c+1, (c+1)&1); }
      if (c < 15) { WAITV(6); } else { WAITV(0); }   // own chunk-c glds landed
      BAR();                                          // everyone's chunk-c landed
      SCHEDB();
      #pragma unroll
      for (int ks = 0; ks < 2; ++ks) {
        bf16x8 afr[2], bfr[4];
        #pragma unroll
        for (int mq = 0; mq < 2; ++mq) {
          int q = wq*32 + mq*16 + lr;
          int sw = (q & 7) << 4;
          int base = (c & 1)*16384 + q*256;
          f32x4 x0 = *reinterpret_cast<const f32x4*>(qb + base + ((ks*128 + lg*32) ^ sw));
          f32x4 x1 = *reinterpret_cast<const f32x4*>(qb + base + ((ks*128 + lg*32 + 16) ^ sw));
          afr[mq] = cvt8(x0, x1);
        }
        #pragma unroll
        for (int ns = 0; ns < 4; ++ns) {
          int s = ws*64 + ns*16 + lr;
          bfr[ns] = *reinterpret_cast<const bf16x8*>(
              bs + (c & 1)*32768 + s*128 + ((ks*64 + lg*16) ^ ((s & 7) << 4)));
        }
        __builtin_amdgcn_s_setprio(1);
        #pragma unroll
        for (int mq = 0; mq < 2; ++mq)
          #pragma unroll
          for (int ns = 0; ns < 4; ++ns)
            qk[mq][ns] = __builtin_amdgcn_mfma_f32_16x16x32_bf16(afr[mq], bfr[ns], qk[mq][ns], 0, 0, 0);
        __builtin_amdgcn_s_setprio(0);
      }
      BAR();          // chunk-c reads retired; next stage may overwrite
      SCHEDB();
    }

    // ================= softmax (m==0) + P + V0 prefetch =================
    stageV(t, 0, 0);                       // latency hidden under softmax VALU
    const float SCL = 0.04508422f;         // (1/32) * log2(e)
    #pragma unroll
    for (int mq = 0; mq < 2; ++mq)
      #pragma unroll
      for (int ns = 0; ns < 4; ++ns)
        #pragma unroll
        for (int j2 = 0; j2 < 4; ++j2) {
          float p = exp2f(qk[mq][ns][j2] * SCL);
          l_acc[mq][j2] += p;
          int q = wq*32 + mq*16 + 4*lg + j2;
          int s = ws*64 + ns*16 + lr;
          *reinterpret_cast<__bf16*>(P + q*512 + ((s*2) ^ ((q & 7) << 4))) = (__bf16)p;
        }
    WAITL();                               // own P ds_writes visible
    BAR();                                 // P visible to all
    SCHEDB();

    // ================= PV : O[64 q][wave's 128 d] += P[64][256] @ V =================
    #pragma unroll
    for (int k = 0; k < 8; ++k) {
      if (k < 7) stageV(t, k+1, (k+1)&1);
      if (k < 7) { WAITV(8); } else { WAITV(0); }
      BAR();
      SCHEDB();
      bf16x8 pa[4];
      #pragma unroll
      for (int mq = 0; mq < 4; ++mq) {
        int q = mq*16 + lr;
        pa[mq] = *reinterpret_cast<const bf16x8*>(
            P + q*512 + ((k*64 + lg*16) ^ ((q & 7) << 4)));
      }
      const u8* vbase = vb + (k & 1)*65536 + (w*128 + lr)*64 + lg*16;
      __builtin_amdgcn_s_setprio(1);
      #pragma unroll
      for (int nf = 0; nf < 8; ++nf) {
        bf16x8 bv = *reinterpret_cast<const bf16x8*>(vbase + nf*16*64);
        #pragma unroll
        for (int mq = 0; mq < 4; ++mq)
          Oacc[mq][nf] = __builtin_amdgcn_mfma_f32_16x16x32_bf16(pa[mq], bv, Oacc[mq][nf], 0, 0, 0);
      }
      __builtin_amdgcn_s_setprio(0);
      BAR();
      SCHEDB();
    }
  } // tiles

  // ================= epilogue: combine l partials, write O =================
  #pragma unroll
  for (int mq = 0; mq < 2; ++mq)
    #pragma unroll
    for (int j2 = 0; j2 < 4; ++j2) {
      float v = l_acc[mq][j2];
      v += __shfl_xor(v, 1);
      v += __shfl_xor(v, 2);
      v += __shfl_xor(v, 4);
      v += __shfl_xor(v, 8);
      l_acc[mq][j2] = v;
    }
  float* lred = (float*)P;
  if (lr == 0) {
    #pragma unroll
    for (int mq = 0; mq < 2; ++mq)
      #pragma unroll
      for (int j2 = 0; j2 < 4; ++j2)
        lred[ws*64 + wq*32 + mq*16 + 4*lg + j2] = l_acc[mq][j2];
  }
  WAITL();
  BAR();

  float* Ob = Og + ((size_t)b*LQ_ + (size_t)qt*BQ_)*DH_;
  #pragma unroll
  for (int mq = 0; mq < 4; ++mq)
    #pragma unroll
    for (int j2 = 0; j2 < 4; ++j2) {
      int q = mq*16 + 4*lg + j2;
      float s = lred[q] + lred[64 + q] + lred[128 + q] + lred[192 + q];
      float rinv = 1.0f / s;
      #pragma unroll
      for (int nf = 0; nf < 8; ++nf)
        Ob[(size_t)q*DH_ + w*128 + nf*16 + lr] = Oacc[mq][nf][j2] * rinv;
    }
}

// ---------------- correctness-only fallback (ws too small; never expected) ----------------
__global__ void attn_naive(const float* __restrict__ Q, const float* __restrict__ S,
                           float* __restrict__ O)
{
  const int row = blockIdx.x;
  const int b = row >> 12, q = row & 4095;
  const float* qp = Q + ((size_t)b*LQ_ + q)*DH_;
  const float* sp = S + (size_t)b*LS_*DH_;
  __shared__ float qs[DH_];
  __shared__ float osum[DH_];
  __shared__ float lsum;
  for (int i = threadIdx.x; i < DH_; i += 256) { qs[i] = qp[i]; osum[i] = 0.f; }
  if (threadIdx.x == 0) lsum = 0.f;
  __syncthreads();
  float lpart = 0.f;
  for (int s0 = threadIdx.x; s0 < LS_; s0 += 256) {
    const float* sr = sp + (size_t)s0*DH_;
    float dot = 0.f;
    for (int d = 0; d < DH_; ++d) dot += qs[d]*sr[d];
    float p = __expf(dot * 0.03125f);
    lpart += p;
    for (int d = 0; d < DH_; ++d) atomicAdd(&osum[d], p*sr[d]);
  }
  atomicAdd(&lsum, lpart);
  __syncthreads();
  float rinv = 1.0f / lsum;
  float* op = O + ((size_t)b*LQ_ + q)*DH_;
  for (int i = threadIdx.x; i < DH_; i += 256) op[i] = osum[i]*rinv;
}

extern "C" void kernel_launch(void* const* d_in, const int* in_sizes, int n_in,
                              void* d_out, int out_size, void* d_ws, size_t ws_size,
                              hipStream_t stream)
{
  const float* Q = (const float*)d_in[0];
  const float* S = (const float*)d_in[1];
  float* out = (float*)d_out;

  const size_t sbt_bytes = (size_t)B_*NT_*16*32768;   // 32 MB
  const size_t vt_bytes  = (size_t)B_*NT_*8*65536;    // 32 MB
  const size_t need = sbt_bytes + vt_bytes;           // 64 MB (same as prior rounds)

  if (ws_size >= need) {
    u8* SbT = (u8*)d_ws;
    u8* VT  = SbT + sbt_bytes;
    cvt_kernel<<<dim3(64, 16, 4), 256, 0, stream>>>(S, SbT, VT);
    attn_kernel<<<dim3(256), NTH, 0, stream>>>(Q, SbT, VT, out);
  } else {
    attn_naive<<<dim3(B_*LQ_), 256, 0, stream>>>(Q, S, out);
  }
}